// Round 9
// baseline (155.691 us; speedup 1.0000x reference)
//
#include <hip/hip_runtime.h>

typedef _Float16 half_t;
typedef __attribute__((ext_vector_type(4))) _Float16 half4;   // 2 VGPRs
typedef __attribute__((ext_vector_type(8))) _Float16 half8;   // MFMA A/B frag (4 VGPRs)
typedef __attribute__((ext_vector_type(4))) float f32x4;      // MFMA C/D frag

#define NPOLY 16384   // B*N
#define PPTS  32
#define CIN   9
#define RSH   36      // fg row stride in halves (72B): breaks q-block bank alignment

__device__ __forceinline__ half8 ld8(const half_t* p){
    return *reinterpret_cast<const half8*>(p);
}
__device__ __forceinline__ f32x4 MFMA(half8 a, half8 b, f32x4 c){
    return __builtin_amdgcn_mfma_f32_16x16x32_f16(a, b, c, 0, 0, 0);
}
// Fragment layouts (measured, learn_hip m89/m120; dtype-independent):
//   A[m][k]: m = lane&15 (+16*mt), k = (lane>>4)*8 + j (+32*ks)
//   B[k][n]: n = lane&15 (+16*nt), k = (lane>>4)*8 + j (+32*ks)
//   C/D[row][col]: col = lane&15 (+16*nt), row = (lane>>4)*4 + r (+16*mt)

// =====================================================================
// LESSONS: (r1) d_ws re-poisoned each iter -> never read it.
// (r2/r5) effective VGPR cap 128; full weight hoist spills. (r3)
// occupancy 3->4 waves/SIMD: no effect. (r4) rolled loop: best 43.6us.
// (r6) stagger/setprio: regression. (r7/r8) ds_read_b64_tr_b16 failed
// twice with identical absmax -> semantics model wrong, ABANDONED.
// Pipe model (r4 counters): per-SIMD VALU ~15%, MFMA ~2.4%, shared DS
// pipe ~57% busy -> DS-bound + dependency stalls. Hot spot: layer-
// boundary epilogue = 64 scalar ds_write_b16 + 8 ds_read_b128/wave-iter.
// THIS ROUND: fg layout [feat][point], 72B row stride.
//  - stores: C/D reg-quad = 4 consecutive points x 1 feat -> packed
//    half4 -> 16 ds_write_b64/wave-iter, imm offsets (was 64 b16).
//  - reads: A-frag = 8 feats x fixed point -> 8 dword loads (fuse to
//    ds_read2_b32), extract own half via (u>>sh)&0xffff (sh lane-const).
//  All plain DS ops; layout algebra hand-verified.
// Block = 512 thr (8 waves) = 32 polylines; grid 512 = 2 blocks/CU.
// =====================================================================
__global__ __launch_bounds__(512, 2) void k_fused(
    const float* __restrict__ px,        // [NPOLY][32][9]
    const int*   __restrict__ pmask,     // [NPOLY][32]
    const float* __restrict__ w_pre, const float* __restrict__ b_pre,
    const float* __restrict__ g_pre, const float* __restrict__ be_pre,
    const float* __restrict__ rm_pre, const float* __restrict__ rv_pre,
    const float* __restrict__ w_m1, const float* __restrict__ b_m1,
    const float* __restrict__ g_m1, const float* __restrict__ be_m1,
    const float* __restrict__ rm_m1, const float* __restrict__ rv_m1,
    const float* __restrict__ w_m2, const float* __restrict__ b_m2,
    const float* __restrict__ g_m2, const float* __restrict__ be_m2,
    const float* __restrict__ rm_m2, const float* __restrict__ rv_m2,
    const float* __restrict__ w1, const float* __restrict__ b1,
    const float* __restrict__ w2, const float* __restrict__ b2,
    float* __restrict__ out)
{
    // encoder weight frags (f16, BN-scaled): pre 0..3, m1 4..19, m2 20..27
    __shared__ __align__(16) half_t lds_w[28 * 512];   // 28 KB
    __shared__ __align__(16) half_t fg[8][64 * RSH];   // 36 KB: [feat][point], 72B rows
    __shared__ __align__(16) half_t pooledb[8][64];    // 1 KB
    __shared__ __align__(16) half_t ft[32 * 72];       // 4.5 KB feat A-tile (32 rows)
    __shared__ __align__(16) half_t qt[32 * 72];       // 4.5 KB out1 A-tile
    __shared__ int maskb[8][2][32];                    // 2 KB (double-buffered)
    __shared__ int validb[32];

    const int tid  = threadIdx.x;
    const int wave = tid >> 6, lane = tid & 63, l15 = lane & 15, q = lane >> 4;

    // ---- stage encoder weights, fp32 -> f16, folding BN scale sA ----
    #pragma unroll 1
    for (int s = tid; s < 28 * 64; s += 512) {
        int frag = s >> 6, ln = s & 63;
        const float *W, *G, *RV; int K, ks, nt;
        if (frag < 4)       { W = w_pre; G = g_pre; RV = rv_pre; K = CIN; ks = 0; nt = frag; }
        else if (frag < 20) { W = w_m1;  G = g_m1;  RV = rv_m1;  K = 128; int f = frag - 4;  ks = f >> 2; nt = f & 3; }
        else                { W = w_m2;  G = g_m2;  RV = rv_m2;  K = 64;  int f = frag - 20; ks = f >> 2; nt = f & 3; }
        int col = nt * 16 + (ln & 15);
        int kb  = ks * 32 + ((ln >> 4) << 3);
        float sA = G[col] * rsqrtf(RV[col] + 1e-5f);
        half_t* dst = &lds_w[s * 8];
        #pragma unroll
        for (int j = 0; j < 8; j++) {
            int k  = kb + j;
            int ka = (k < K) ? k : 0;
            float v = W[ka * 64 + col] * sA;
            dst[j] = (k < K) ? (half_t)v : (half_t)0.f;
        }
    }

    // ---- per-lane BN bias consts (go into MFMA acc init), h = nt*16+l15 ----
    float sC0[4], sC1[4], sC2[4];
    #pragma unroll
    for (int nt = 0; nt < 4; nt++) {
        int h = nt * 16 + l15; float a;
        a = g_pre[h] * rsqrtf(rv_pre[h] + 1e-5f); sC0[nt] = (b_pre[h] - rm_pre[h]) * a + be_pre[h];
        a = g_m1[h]  * rsqrtf(rv_m1[h]  + 1e-5f); sC1[nt] = (b_m1[h]  - rm_m1[h])  * a + be_m1[h];
        a = g_m2[h]  * rsqrtf(rv_m2[h]  + 1e-5f); sC2[nt] = (b_m2[h]  - rm_m2[h])  * a + be_m2[h];
    }

    const int nbase = blockIdx.x * 32 + wave * 4;

    // ---- fg bases ----
    // store: value(pt=4q+r+16mt, feat=16nt+l15) at halves
    //   (16nt+l15)*RSH + 4q + 16mt  ->  base l15*RSH + q*4, imm nt*16*RSH + mt*16
    half_t* const fgw   = &fg[wave][0];
    half_t* const fg_st = fgw + l15 * RSH + q * 4;
    // read: feat=32ks+8q+j row, point-pair dword containing l15 (+16mt):
    //   byte = (32ks+8q+j)*72 + (l15>>1)*4 + mt*32 -> base q*576 + (l15>>1)*4
    const char* const fg_rb = (const char*)fgw + q * 576 + (l15 >> 1) * 4;
    const unsigned sh = (unsigned)((l15 & 1) * 16);
    const half_t* const lwb = lds_w + lane * 8;
    half_t* const pbw = &pooledb[wave][0];

    // ---- prefetch iter 0 x (lanes q<2) and mask (lanes 32..63) ----
    float xr[2][8];
    #pragma unroll
    for (int mt = 0; mt < 2; mt++) {
        const float* src = px + ((long)nbase * PPTS + l15 + 16 * mt) * CIN;
        if (q == 0) {
            #pragma unroll
            for (int j = 0; j < 8; j++) xr[mt][j] = src[j];
        } else if (q == 1) {
            xr[mt][0] = src[8];
        }
    }
    if (lane >= 32) maskb[wave][0][lane - 32] = pmask[nbase * PPTS + (lane - 32)];

    __syncthreads();   // weights staged

    // pre-layer B-frags reused every iteration: hoist to registers
    half8 preb[4];
    #pragma unroll
    for (int nt = 0; nt < 4; nt++) preb[nt] = ld8(lwb + nt * 512);

    // ---- main loop: rolled (r4 lesson) ----
    #pragma unroll 1
    for (int it = 0; it < 4; ++it) {
        const int n = nbase + it;

        // ---- issue next-iteration prefetch loads ----
        float xn[2][8]; int mnext = 0;
        if (it < 3) {
            #pragma unroll
            for (int mt = 0; mt < 2; mt++) {
                const float* src = px + ((long)(n + 1) * PPTS + l15 + 16 * mt) * CIN;
                if (q == 0) {
                    #pragma unroll
                    for (int j = 0; j < 8; j++) xn[mt][j] = src[j];
                } else if (q == 1) {
                    xn[mt][0] = src[8];
                }
            }
            if (lane >= 32) mnext = pmask[(n + 1) * PPTS + (lane - 32)];
        }

        // ---- build x A-frags (K=9 zero-padded to 32) ----
        half8 xa[2];
        #pragma unroll
        for (int mt = 0; mt < 2; mt++) {
            half8 v;
            #pragma unroll
            for (int j = 0; j < 8; j++) v[j] = (half_t)0.f;
            if (q == 0) {
                #pragma unroll
                for (int j = 0; j < 8; j++) v[j] = (half_t)xr[mt][j];
            } else if (q == 1) {
                v[0] = (half_t)xr[mt][0];
            }
            xa[mt] = v;
        }

        // ---- pre layer: acc init = sC0 (BN bias) ----
        f32x4 acc[2][4];
        #pragma unroll
        for (int mt = 0; mt < 2; mt++)
            #pragma unroll
            for (int nt = 0; nt < 4; nt++)
                #pragma unroll
                for (int r = 0; r < 4; r++) acc[mt][nt][r] = sC0[nt];

        #pragma unroll
        for (int nt = 0; nt < 4; nt++) {
            acc[0][nt] = MFMA(xa[0], preb[nt], acc[0][nt]);
            acc[1][nt] = MFMA(xa[1], preb[nt], acc[1][nt]);
        }

        float maskf[8];
        #pragma unroll
        for (int mt = 0; mt < 2; mt++)
            #pragma unroll
            for (int r = 0; r < 4; r++)
                maskf[mt * 4 + r] = maskb[wave][it & 1][mt * 16 + q * 4 + r] ? 1.f : 0.f;

        // ReLU+mask -> packed half4 [feat][point] stores; track pooled max
        float pm[4];
        #pragma unroll
        for (int nt = 0; nt < 4; nt++) {
            float m = 0.f;
            #pragma unroll
            for (int mt = 0; mt < 2; mt++) {
                float v0 = fmaxf(acc[mt][nt][0], 0.f) * maskf[mt * 4 + 0];
                float v1 = fmaxf(acc[mt][nt][1], 0.f) * maskf[mt * 4 + 1];
                float v2 = fmaxf(acc[mt][nt][2], 0.f) * maskf[mt * 4 + 2];
                float v3 = fmaxf(acc[mt][nt][3], 0.f) * maskf[mt * 4 + 3];
                half4 h; h[0] = (half_t)v0; h[1] = (half_t)v1; h[2] = (half_t)v2; h[3] = (half_t)v3;
                *reinterpret_cast<half4*>(fg_st + nt * (16 * RSH) + mt * 16) = h;
                m = fmaxf(m, fmaxf(fmaxf(v0, v1), fmaxf(v2, v3)));
            }
            m = fmaxf(m, __shfl_xor(m, 16));
            m = fmaxf(m, __shfl_xor(m, 32));
            pm[nt] = m;
        }
        {
            float pv = (q == 0) ? pm[0] : (q == 1) ? pm[1] : (q == 2) ? pm[2] : pm[3];
            pbw[lane] = (half_t)pv;   // col = q*16+l15 = lane
        }

        // ---- l1: A = [f | pooled-bcast] (32x128) @ (128x64), init sC1 ----
        f32x4 acc1[2][4];
        #pragma unroll
        for (int mt = 0; mt < 2; mt++)
            #pragma unroll
            for (int nt = 0; nt < 4; nt++)
                #pragma unroll
                for (int r = 0; r < 4; r++) acc1[mt][nt][r] = sC1[nt];

        half8 pa0 = ld8(pbw + q * 8);
        half8 pa1 = ld8(pbw + 32 + q * 8);

        // A-frags: 8 dword reads per frag (feat rows), extract own half
        half8 af[2][2];   // [mt][ks]
        #pragma unroll
        for (int mt = 0; mt < 2; mt++)
            #pragma unroll
            for (int ks = 0; ks < 2; ks++) {
                union { unsigned u[4]; half8 h; } cv;
                #pragma unroll
                for (int t = 0; t < 4; t++) {
                    unsigned lo = *(const unsigned*)(fg_rb + ks * 2304 + (2 * t) * 72 + mt * 32);
                    unsigned hi = *(const unsigned*)(fg_rb + ks * 2304 + (2 * t + 1) * 72 + mt * 32);
                    cv.u[t] = ((lo >> sh) & 0xffffu) | (((hi >> sh) & 0xffffu) << 16);
                }
                af[mt][ks] = cv.h;
            }

        #pragma unroll
        for (int ks = 0; ks < 2; ks++) {
            #pragma unroll
            for (int nt = 0; nt < 4; nt++) {
                half8 b = ld8(lwb + (4 + ks * 4 + nt) * 512);
                acc1[0][nt] = MFMA(af[0][ks], b, acc1[0][nt]);
                acc1[1][nt] = MFMA(af[1][ks], b, acc1[1][nt]);
            }
        }
        #pragma unroll
        for (int ks = 2; ks < 4; ks++) {
            half8 ap = (ks == 2) ? pa0 : pa1;
            #pragma unroll
            for (int nt = 0; nt < 4; nt++) {
                half8 b = ld8(lwb + (4 + ks * 4 + nt) * 512);
                acc1[0][nt] = MFMA(ap, b, acc1[0][nt]);
                acc1[1][nt] = MFMA(ap, b, acc1[1][nt]);
            }
        }

        // ReLU only -> packed stores (overwrite f with g)
        #pragma unroll
        for (int nt = 0; nt < 4; nt++)
            #pragma unroll
            for (int mt = 0; mt < 2; mt++) {
                half4 h;
                h[0] = (half_t)fmaxf(acc1[mt][nt][0], 0.f);
                h[1] = (half_t)fmaxf(acc1[mt][nt][1], 0.f);
                h[2] = (half_t)fmaxf(acc1[mt][nt][2], 0.f);
                h[3] = (half_t)fmaxf(acc1[mt][nt][3], 0.f);
                *reinterpret_cast<half4*>(fg_st + nt * (16 * RSH) + mt * 16) = h;
            }

        // ---- l2: (32x64) @ (64x64), init sC2 ----
        f32x4 acc2[2][4];
        #pragma unroll
        for (int mt = 0; mt < 2; mt++)
            #pragma unroll
            for (int nt = 0; nt < 4; nt++)
                #pragma unroll
                for (int r = 0; r < 4; r++) acc2[mt][nt][r] = sC2[nt];

        half8 ag[2][2];
        #pragma unroll
        for (int mt = 0; mt < 2; mt++)
            #pragma unroll
            for (int ks = 0; ks < 2; ks++) {
                union { unsigned u[4]; half8 h; } cv;
                #pragma unroll
                for (int t = 0; t < 4; t++) {
                    unsigned lo = *(const unsigned*)(fg_rb + ks * 2304 + (2 * t) * 72 + mt * 32);
                    unsigned hi = *(const unsigned*)(fg_rb + ks * 2304 + (2 * t + 1) * 72 + mt * 32);
                    cv.u[t] = ((lo >> sh) & 0xffffu) | (((hi >> sh) & 0xffffu) << 16);
                }
                ag[mt][ks] = cv.h;
            }

        #pragma unroll
        for (int ks = 0; ks < 2; ks++) {
            #pragma unroll
            for (int nt = 0; nt < 4; nt++) {
                half8 b = ld8(lwb + (20 + ks * 4 + nt) * 512);
                acc2[0][nt] = MFMA(ag[0][ks], b, acc2[0][nt]);
                acc2[1][nt] = MFMA(ag[1][ks], b, acc2[1][nt]);
            }
        }

        // ReLU+mask, masked max over points -> feat row into ft tile
        float fm[4];
        #pragma unroll
        for (int nt = 0; nt < 4; nt++) {
            float m = 0.f;
            #pragma unroll
            for (int mt = 0; mt < 2; mt++)
                #pragma unroll
                for (int r = 0; r < 4; r++) {
                    float v = fmaxf(acc2[mt][nt][r], 0.f) * maskf[mt * 4 + r];
                    m = fmaxf(m, v);
                }
            m = fmaxf(m, __shfl_xor(m, 16));
            m = fmaxf(m, __shfl_xor(m, 32));
            fm[nt] = m;
        }
        float fv = (q == 0) ? fm[0] : (q == 1) ? fm[1] : (q == 2) ? fm[2] : fm[3];
        ft[(wave * 4 + it) * 72 + lane] = (half_t)fv;   // row = 4w+it, col = lane

        int lm = 0;
        #pragma unroll
        for (int j = 0; j < 8; j++) lm |= (maskf[j] != 0.f);
        unsigned long long bal = __ballot(lm);
        if (lane == 0) validb[wave * 4 + it] = bal ? 1 : 0;

        // ---- commit prefetch for next iteration ----
        if (it < 3) {
            if (lane >= 32) maskb[wave][(it + 1) & 1][lane - 32] = mnext;
            #pragma unroll
            for (int mt = 0; mt < 2; mt++)
                #pragma unroll
                for (int j = 0; j < 8; j++) xr[mt][j] = xn[mt][j];
        }
    }

    // =============== out-MLP stage (M=32 rows per block) ===============
    // 8 waves <-> 8 tiles: wave w owns (mt_o = w>>2, nt1 = w&3) for out1,
    // cols nt1 and nt1+4 for out2. B-frags straight from global (L2).
    const int mt_o = wave >> 2, nt1 = wave & 3;
    float bb1 = b1[nt1 * 16 + l15];
    half8 bw1[2];
    #pragma unroll
    for (int ks = 0; ks < 2; ks++)
        #pragma unroll
        for (int j = 0; j < 8; j++)
            bw1[ks][j] = (half_t)w1[(ks * 32 + q * 8 + j) * 64 + nt1 * 16 + l15];

    float bb2[2];
    half8 bw2[2][2];   // [ks][t]
    #pragma unroll
    for (int t = 0; t < 2; t++) {
        int c = (nt1 + 4 * t) * 16 + l15;
        bb2[t] = b2[c];
        #pragma unroll
        for (int ks = 0; ks < 2; ks++)
            #pragma unroll
            for (int j = 0; j < 8; j++)
                bw2[ks][t][j] = (half_t)w2[(ks * 32 + q * 8 + j) * 128 + c];
    }

    __syncthreads();   // ft + validb complete

    // out1: wave w computes rows mt_o*16.., cols nt1*16..
    f32x4 o1;
    #pragma unroll
    for (int r = 0; r < 4; r++) o1[r] = bb1;
    #pragma unroll
    for (int ks = 0; ks < 2; ks++) {
        half8 a = ld8(&ft[(mt_o * 16 + l15) * 72 + ks * 32 + q * 8]);
        o1 = MFMA(a, bw1[ks], o1);
    }
    #pragma unroll
    for (int r = 0; r < 4; r++) {
        float v = fmaxf(o1[r], 0.f);
        qt[(mt_o * 16 + q * 4 + r) * 72 + nt1 * 16 + l15] = (half_t)v;
    }

    __syncthreads();   // qt complete

    // out2: wave w computes rows mt_o*16.., cols nt1*16 and (nt1+4)*16
    f32x4 o2[2];
    #pragma unroll
    for (int t = 0; t < 2; t++)
        #pragma unroll
        for (int r = 0; r < 4; r++) o2[t][r] = bb2[t];
    #pragma unroll
    for (int ks = 0; ks < 2; ks++) {
        half8 a = ld8(&qt[(mt_o * 16 + l15) * 72 + ks * 32 + q * 8]);
        o2[0] = MFMA(a, bw2[ks][0], o2[0]);
        o2[1] = MFMA(a, bw2[ks][1], o2[1]);
    }
    #pragma unroll
    for (int r = 0; r < 4; r++) {
        int row = mt_o * 16 + q * 4 + r;
        float vr = validb[row] ? 1.f : 0.f;
        long rowg = (long)(blockIdx.x * 32 + row);
        out[rowg * 128 + (nt1 + 0) * 16 + l15] = o2[0][r] * vr;
        out[rowg * 128 + (nt1 + 4) * 16 + l15] = o2[1][r] * vr;
    }
}

extern "C" void kernel_launch(void* const* d_in, const int* in_sizes, int n_in,
                              void* d_out, int out_size, void* d_ws, size_t ws_size,
                              hipStream_t stream) {
    (void)in_sizes; (void)n_in; (void)out_size; (void)d_ws; (void)ws_size;
    k_fused<<<dim3(NPOLY / 32), dim3(512), 0, stream>>>(
        (const float*)d_in[0], (const int*)d_in[1],
        (const float*)d_in[2],  (const float*)d_in[3],  (const float*)d_in[4],
        (const float*)d_in[5],  (const float*)d_in[6],  (const float*)d_in[7],
        (const float*)d_in[8],  (const float*)d_in[9],  (const float*)d_in[10],
        (const float*)d_in[11], (const float*)d_in[12], (const float*)d_in[13],
        (const float*)d_in[14], (const float*)d_in[15], (const float*)d_in[16],
        (const float*)d_in[17], (const float*)d_in[18], (const float*)d_in[19],
        (const float*)d_in[20], (const float*)d_in[21],
        (const float*)d_in[22], (const float*)d_in[23],
        (float*)d_out);
}